// Round 1
// baseline (134.828 us; speedup 1.0000x reference)
//
#include <hip/hip_runtime.h>

#define NN 50000
#define NE 600000
#define DI 128
#define DH 16
#define DC 8

// ---------------- layer-1 GEMM: xl = x @ W1l, xr = x @ W1r ----------------
__global__ __launch_bounds__(256) void k_gemm1(
    const float* __restrict__ x,
    const float* __restrict__ W1l,
    const float* __restrict__ W1r,
    float* __restrict__ xl,
    float* __restrict__ xr)
{
    __shared__ float Wc[DI][32];   // [k][j]: j<16 -> W1l, j>=16 -> W1r
    for (int i = threadIdx.x; i < DI * DH; i += 256) {
        int k = i >> 4, j = i & 15;
        Wc[k][j]      = W1l[i];
        Wc[k][j + 16] = W1r[i];
    }
    __syncthreads();
    int n = blockIdx.x * 256 + threadIdx.x;
    if (n >= NN) return;

    float acc[32];
#pragma unroll
    for (int j = 0; j < 32; ++j) acc[j] = 0.f;

    const float4* xrow = (const float4*)(x + (size_t)n * DI);
#pragma unroll 2
    for (int k4 = 0; k4 < DI / 4; ++k4) {
        float4 xv = xrow[k4];
        float xa[4] = {xv.x, xv.y, xv.z, xv.w};
#pragma unroll
        for (int kk = 0; kk < 4; ++kk) {
            const float4* wr = (const float4*)(Wc[k4 * 4 + kk]);
#pragma unroll
            for (int j4 = 0; j4 < 8; ++j4) {
                float4 w = wr[j4];
                acc[j4 * 4 + 0] += xa[kk] * w.x;
                acc[j4 * 4 + 1] += xa[kk] * w.y;
                acc[j4 * 4 + 2] += xa[kk] * w.z;
                acc[j4 * 4 + 3] += xa[kk] * w.w;
            }
        }
    }
    float4* o1 = (float4*)(xl + (size_t)n * DH);
    float4* o2 = (float4*)(xr + (size_t)n * DH);
#pragma unroll
    for (int q = 0; q < 4; ++q) {
        o1[q] = make_float4(acc[q*4+0], acc[q*4+1], acc[q*4+2], acc[q*4+3]);
        o2[q] = make_float4(acc[16+q*4+0], acc[16+q*4+1], acc[16+q*4+2], acc[16+q*4+3]);
    }
}

// ------------- scatter-add: agg[dst][f] += v[src][f]; optional count -------------
template <int F>
__global__ __launch_bounds__(256) void k_scatter(
    const int* __restrict__ src, const int* __restrict__ dst,
    const float* __restrict__ v, float* __restrict__ agg,
    float* __restrict__ cnt)
{
    int t = blockIdx.x * 256 + threadIdx.x;
    if (t >= NE * F) return;
    int e = t / F, f = t & (F - 1);
    int s = src[e], d = dst[e];
    atomicAdd(&agg[d * F + f], v[s * F + f]);
    if (cnt != nullptr && f == 0) atomicAdd(&cnt[d], 1.0f);
}

// -------- layer-1 finish + layer-2 GEMM: h = relu(agg1/cnt + b1 + xr); zl=h@W2l; zr=h@W2r --------
__global__ __launch_bounds__(256) void k_layer(
    const float* __restrict__ agg1, const float* __restrict__ cnt,
    const float* __restrict__ xr, const float* __restrict__ b1,
    const float* __restrict__ W2l, const float* __restrict__ W2r,
    float* __restrict__ zl, float* __restrict__ zr)
{
    __shared__ float W2[DH][16];   // [k][j]: j<8 -> W2l, j>=8 -> W2r
    __shared__ float b1s[DH];
    if (threadIdx.x < DH * DC) {
        int k = threadIdx.x >> 3, j = threadIdx.x & 7;
        W2[k][j]     = W2l[threadIdx.x];
        W2[k][j + 8] = W2r[threadIdx.x];
    }
    if (threadIdx.x < DH) b1s[threadIdx.x] = b1[threadIdx.x];
    __syncthreads();

    int n = blockIdx.x * 256 + threadIdx.x;
    if (n >= NN) return;

    float inv = 1.0f / fmaxf(cnt[n], 1.0f);
    const float4* ap = (const float4*)(agg1 + (size_t)n * DH);
    const float4* rp = (const float4*)(xr + (size_t)n * DH);
    float h[DH];
#pragma unroll
    for (int q = 0; q < 4; ++q) {
        float4 a = ap[q], r = rp[q];
        h[q*4+0] = fmaxf(a.x * inv + b1s[q*4+0] + r.x, 0.f);
        h[q*4+1] = fmaxf(a.y * inv + b1s[q*4+1] + r.y, 0.f);
        h[q*4+2] = fmaxf(a.z * inv + b1s[q*4+2] + r.z, 0.f);
        h[q*4+3] = fmaxf(a.w * inv + b1s[q*4+3] + r.w, 0.f);
    }

    float acc[16];
#pragma unroll
    for (int j = 0; j < 16; ++j) acc[j] = 0.f;
#pragma unroll
    for (int k = 0; k < DH; ++k) {
        const float4* wr = (const float4*)(W2[k]);
        float hs = h[k];
#pragma unroll
        for (int j4 = 0; j4 < 4; ++j4) {
            float4 w = wr[j4];
            acc[j4*4+0] += hs * w.x;
            acc[j4*4+1] += hs * w.y;
            acc[j4*4+2] += hs * w.z;
            acc[j4*4+3] += hs * w.w;
        }
    }
    float4* zlo = (float4*)(zl + (size_t)n * DC);
    float4* zro = (float4*)(zr + (size_t)n * DC);
    zlo[0] = make_float4(acc[0], acc[1], acc[2], acc[3]);
    zlo[1] = make_float4(acc[4], acc[5], acc[6], acc[7]);
    zro[0] = make_float4(acc[8], acc[9], acc[10], acc[11]);
    zro[1] = make_float4(acc[12], acc[13], acc[14], acc[15]);
}

// -------- epilogue: out = agg2/cnt + b2 + zr --------
__global__ __launch_bounds__(256) void k_out(
    const float* __restrict__ agg2, const float* __restrict__ cnt,
    const float* __restrict__ zr, const float* __restrict__ b2,
    float* __restrict__ out)
{
    int t = blockIdx.x * 256 + threadIdx.x;
    if (t >= NN * DC) return;
    int n = t >> 3, f = t & 7;
    float inv = 1.0f / fmaxf(cnt[n], 1.0f);
    out[t] = agg2[t] * inv + b2[f] + zr[t];
}

extern "C" void kernel_launch(void* const* d_in, const int* in_sizes, int n_in,
                              void* d_out, int out_size, void* d_ws, size_t ws_size,
                              hipStream_t stream)
{
    const float* x   = (const float*)d_in[0];
    const int*   ei  = (const int*)d_in[1];
    const float* W1l = (const float*)d_in[2];
    const float* b1  = (const float*)d_in[3];
    const float* W1r = (const float*)d_in[4];
    const float* W2l = (const float*)d_in[5];
    const float* b2  = (const float*)d_in[6];
    const float* W2r = (const float*)d_in[7];
    float* out = (float*)d_out;

    float* ws   = (float*)d_ws;
    float* xl   = ws;                    // NN*16
    float* xr   = xl + NN * DH;          // NN*16
    float* agg1 = xr + NN * DH;          // NN*16 (zeroed)
    float* cnt  = agg1 + NN * DH;        // NN    (zeroed, adjacent to agg1)
    float* zl   = cnt + NN;              // NN*8
    float* zr   = zl + NN * DC;          // NN*8
    float* agg2 = zr + NN * DC;          // NN*8 (zeroed)

    const int* src = ei;
    const int* dst = ei + NE;

    hipMemsetAsync(agg1, 0, (size_t)(NN * DH + NN) * sizeof(float), stream);
    hipMemsetAsync(agg2, 0, (size_t)(NN * DC) * sizeof(float), stream);

    k_gemm1<<<(NN + 255) / 256, 256, 0, stream>>>(x, W1l, W1r, xl, xr);
    k_scatter<DH><<<(NE * DH + 255) / 256, 256, 0, stream>>>(src, dst, xl, agg1, cnt);
    k_layer<<<(NN + 255) / 256, 256, 0, stream>>>(agg1, cnt, xr, b1, W2l, W2r, zl, zr);
    k_scatter<DC><<<(NE * DC + 255) / 256, 256, 0, stream>>>(src, dst, zl, agg2, nullptr);
    k_out<<<(NN * DC + 255) / 256, 256, 0, stream>>>(agg2, cnt, zr, b2, out);
}